// Round 4
// baseline (20071.214 us; speedup 1.0000x reference)
//
#include <hip/hip_runtime.h>
#include <hip/hip_bf16.h>
#include <math.h>

#define B_   4096
#define T_   16
#define F_   256
#define U_   512
#define M_   8
#define K_   768    // F+U
#define NRS  4096   // U*M
#define LNT  1.1512925f  // 0.5*ln(10)

// ---------------------------------------------------------------------------
// Correctness-first fp32 VALU GEMM. C[M,N] = A[M,K] @ W[K,N] + bias,
// optional tanh. 64x64 tile, BK=16, 256 threads = 16x16, 4x4 per thread.
// ---------------------------------------------------------------------------
template<int TANH>
__global__ __launch_bounds__(256) void gemm_nn(
    const float* __restrict__ A,
    const float* __restrict__ W,
    const float* __restrict__ bias,
    float* __restrict__ C,
    int N)
{
    __shared__ float As[64][16];
    __shared__ float Ws[16][64 + 1];

    const int tx = threadIdx.x & 15;   // n-dir
    const int ty = threadIdx.x >> 4;   // m-dir
    const int m0 = blockIdx.x * 64;
    const int n0 = blockIdx.y * 64;

    float acc[4][4] = {};

    for (int kk = 0; kk < K_; kk += 16) {
        for (int p = threadIdx.x; p < 64 * 16; p += 256) {
            int r = p >> 4, c = p & 15;
            As[r][c] = A[(size_t)(m0 + r) * K_ + kk + c];
        }
        for (int p = threadIdx.x; p < 16 * 64; p += 256) {
            int r = p >> 6, c = p & 63;
            Ws[r][c] = W[(size_t)(kk + r) * N + n0 + c];
        }
        __syncthreads();
#pragma unroll
        for (int k = 0; k < 16; k++) {
            float a[4], w[4];
#pragma unroll
            for (int i = 0; i < 4; i++) a[i] = As[ty * 4 + i][k];
#pragma unroll
            for (int j = 0; j < 4; j++) w[j] = Ws[k][tx * 4 + j];
#pragma unroll
            for (int i = 0; i < 4; i++)
#pragma unroll
                for (int j = 0; j < 4; j++) acc[i][j] += a[i] * w[j];
        }
        __syncthreads();
    }

#pragma unroll
    for (int i = 0; i < 4; i++) {
        int gr = m0 + ty * 4 + i;
#pragma unroll
        for (int j = 0; j < 4; j++) {
            int gc = n0 + tx * 4 + j;
            float v = acc[i][j] + bias[gc];
            if (TANH) v = tanhf(v);
            C[(size_t)gr * N + gc] = v;
        }
    }
}

// fused[b, 0:256] = x[b,t,:]; fused[b, 256+u] = sum_m hhat[b,u,m]  (fp32)
__global__ void fused_build(const float* __restrict__ x, int t,
                            const float* __restrict__ hhat,
                            float* __restrict__ fused) {
    int idx = blockIdx.x * 256 + threadIdx.x;
    int b = idx / K_;
    int j = idx - b * K_;
    if (j < F_) {
        fused[idx] = x[((size_t)b * T_ + t) * F_ + j];
    } else {
        int u = j - F_;
        const float* hp = hhat + ((size_t)b * U_ + u) * M_;
        float s = 0.f;
#pragma unroll
        for (int m = 0; m < M_; m++) s += hp[m];
        fused[idx] = s;
    }
}

// qin[b,0:256]=x_t; qin[b,256+u] = sum_m softmax_m(-(R[b,u,m]-LNT*m)^2) * hhat[b,u,m]
__global__ void rq_build(const float* __restrict__ x, int t,
                         const float* __restrict__ Rb,
                         const float* __restrict__ hhat,
                         float* __restrict__ qin) {
    int idx = blockIdx.x * 256 + threadIdx.x;
    int b = idx / K_;
    int j = idx - b * K_;
    if (j < F_) {
        qin[idx] = x[((size_t)b * T_ + t) * F_ + j];
    } else {
        int u = j - F_;
        const float* rp = Rb + (size_t)b * NRS + u * M_;
        const float* hp = hhat + ((size_t)b * U_ + u) * M_;
        float z[M_], mx = -1e30f;
#pragma unroll
        for (int m = 0; m < M_; m++) {
            float d = rp[m] - m * LNT;
            z[m] = -d * d;
            mx = fmaxf(mx, z[m]);
        }
        float den = 0.f, num = 0.f;
#pragma unroll
        for (int m = 0; m < M_; m++) {
            float e = expf(z[m] - mx);
            den += e;
            num += e * hp[m];
        }
        qin[idx] = num / den;
    }
}

// s_ki softmax, state update, h-sum. idx = b*U_+u.
__global__ void update_k(const float* __restrict__ Sb,
                         const float* __restrict__ qk,
                         float* __restrict__ hhat,
                         float* __restrict__ hsum) {
    int idx = blockIdx.x * 256 + threadIdx.x;  // B_*U_
    const float* sp = Sb + (size_t)idx * 8;
    float* hp = hhat + (size_t)idx * 8;
    float q = qk[idx];
    float z[M_], mx = -1e30f;
#pragma unroll
    for (int m = 0; m < M_; m++) {
        float d = sp[m] - m * LNT;
        z[m] = -d * d;
        mx = fmaxf(mx, z[m]);
    }
    float den = 0.f;
    float e[M_];
#pragma unroll
    for (int m = 0; m < M_; m++) { e[m] = expf(z[m] - mx); den += e[m]; }
    float hs = 0.f;
#pragma unroll
    for (int m = 0; m < M_; m++) {
        float s = e[m] / den;
        float dec = expf(-0.04f / (m * LNT + 1e-7f));  // m=0 -> 0
        float hn = ((1.f - s) * hp[m] + s * q) * dec;
        hp[m] = hn;
        hs += hn;
    }
    hsum[idx] = hs;
}

// out[b,t,:] = hsum[b,:] @ Wout[512,3] + bout   (one wave per b), fp32 out
__global__ void out_k(const float* __restrict__ hsum,
                      const float* __restrict__ Wout,
                      const float* __restrict__ bout,
                      float* __restrict__ out, int t) {
    int b = blockIdx.x;
    int lane = threadIdx.x;  // 64
    float p0 = 0, p1 = 0, p2 = 0;
    for (int u = lane; u < U_; u += 64) {
        float h = hsum[(size_t)b * U_ + u];
        p0 += h * Wout[u * 3 + 0];
        p1 += h * Wout[u * 3 + 1];
        p2 += h * Wout[u * 3 + 2];
    }
    for (int off = 32; off; off >>= 1) {
        p0 += __shfl_down(p0, off, 64);
        p1 += __shfl_down(p1, off, 64);
        p2 += __shfl_down(p2, off, 64);
    }
    if (lane == 0) {
        size_t o = ((size_t)b * T_ + t) * 3;
        out[o + 0] = p0 + bout[0];
        out[o + 1] = p1 + bout[1];
        out[o + 2] = p2 + bout[2];
    }
}

extern "C" void kernel_launch(void* const* d_in, const int* in_sizes, int n_in,
                              void* d_out, int out_size, void* d_ws, size_t ws_size,
                              hipStream_t stream) {
    const float* x   = (const float*)d_in[0];
    const float* W_r = (const float*)d_in[1];
    const float* b_r = (const float*)d_in[2];
    const float* W_q = (const float*)d_in[3];
    const float* b_q = (const float*)d_in[4];
    const float* W_s = (const float*)d_in[5];
    const float* b_s = (const float*)d_in[6];
    const float* W_o = (const float*)d_in[7];
    const float* b_o = (const float*)d_in[8];
    float* out = (float*)d_out;   // reference output dtype is float32

    char* ws = (char*)d_ws;
    float* hhat = (float*)ws;  ws += (size_t)B_ * U_ * M_ * 4;   // 64 MB
    float* RS   = (float*)ws;  ws += (size_t)B_ * NRS * 4;       // 64 MB (R then S)
    float* qk   = (float*)ws;  ws += (size_t)B_ * U_ * 4;        // 8 MB
    float* hsum = (float*)ws;  ws += (size_t)B_ * U_ * 4;        // 8 MB
    float* fusedF = (float*)ws; ws += (size_t)B_ * K_ * 4;       // 12.6 MB
    float* qinF   = (float*)ws; ws += (size_t)B_ * K_ * 4;       // 12.6 MB

    hipMemsetAsync(hhat, 0, (size_t)B_ * U_ * M_ * 4, stream);

    for (int t = 0; t < T_; t++) {
        fused_build<<<B_ * K_ / 256, 256, 0, stream>>>(x, t, hhat, fusedF);
        gemm_nn<0><<<dim3(64, 64), 256, 0, stream>>>(fusedF, W_r, b_r, RS, NRS);
        rq_build<<<B_ * K_ / 256, 256, 0, stream>>>(x, t, RS, hhat, qinF);
        gemm_nn<0><<<dim3(64, 64), 256, 0, stream>>>(fusedF, W_s, b_s, RS, NRS);
        gemm_nn<1><<<dim3(64, 8), 256, 0, stream>>>(qinF, W_q, b_q, qk, U_);
        update_k<<<B_ * U_ / 256, 256, 0, stream>>>(RS, qk, hhat, hsum);
        out_k<<<B_, 64, 0, stream>>>(hsum, W_o, b_o, out, t);
    }
}

// Round 5
// 2868.771 us; speedup vs baseline: 6.9965x; 6.9965x over previous
//
#include <hip/hip_runtime.h>
#include <hip/hip_bf16.h>
#include <math.h>

#define B_   4096
#define T_   16
#define F_   256
#define U_   512
#define M_   8
#define K_   768    // F+U
#define NRS  4096   // U*M
#define LNT  1.1512925f  // 0.5*ln(10)

typedef __bf16 bf16_t;
typedef bf16_t bf16x8 __attribute__((ext_vector_type(8)));
typedef float  f32x4  __attribute__((ext_vector_type(4)));

__device__ inline void gl_lds16(const void* g, void* lds) {
    __builtin_amdgcn_global_load_lds(
        (const __attribute__((address_space(1))) unsigned int*)g,
        (__attribute__((address_space(3))) unsigned int*)lds, 16, 0, 0);
}

// C = A[M_,K] @ Bt[N,K]^T + bias, optional tanh. A,Bt bf16; bias,C fp32.
// m97 structure: 128x128 tile, BK=32, 4 waves each 64x64, global_load_lds(16B).
template<int TANH>
__global__ __launch_bounds__(256) void gemm_bt(
    const bf16_t* __restrict__ A,
    const bf16_t* __restrict__ Bt,
    const float* __restrict__ bias,
    float* __restrict__ C,
    int N)
{
    __shared__ bf16_t Al[128 * 32];
    __shared__ bf16_t Bl[128 * 32];

    const int tid  = threadIdx.x;
    const int lane = tid & 63;
    const int wave = tid >> 6;
    const int m0 = blockIdx.x * 128;
    const int n0 = blockIdx.y * 128;
    const int wm = (wave & 1) * 64;
    const int wn = (wave >> 1) * 64;
    const int lr = lane & 15;
    const int kq = lane >> 4;

    f32x4 acc[4][4] = {};

    // staging: 8KB tile = 512 x 16B chunks; 256 threads x 2 passes
    const int c0 = tid, c1 = tid + 256;
    const int r0 = c0 >> 2, kc0 = (c0 & 3) * 8;
    const int r1 = c1 >> 2, kc1 = (c1 & 3) * 8;

    for (int kk = 0; kk < K_; kk += 32) {
        __syncthreads();  // prior iter's ds_reads consumed -> safe to overwrite
        gl_lds16(A  + (size_t)(m0 + r0) * K_ + kk + kc0, (char*)Al + c0 * 16);
        gl_lds16(A  + (size_t)(m0 + r1) * K_ + kk + kc1, (char*)Al + c1 * 16);
        gl_lds16(Bt + (size_t)(n0 + r0) * K_ + kk + kc0, (char*)Bl + c0 * 16);
        gl_lds16(Bt + (size_t)(n0 + r1) * K_ + kk + kc1, (char*)Bl + c1 * 16);
        __syncthreads();  // compiler emits vmcnt(0) drain before s_barrier

        bf16x8 af[4], bf[4];
#pragma unroll
        for (int i = 0; i < 4; i++)
            af[i] = *(const bf16x8*)(Al + (wm + i * 16 + lr) * 32 + kq * 8);
#pragma unroll
        for (int i = 0; i < 4; i++)
            bf[i] = *(const bf16x8*)(Bl + (wn + i * 16 + lr) * 32 + kq * 8);
#pragma unroll
        for (int i = 0; i < 4; i++)
#pragma unroll
            for (int j = 0; j < 4; j++)
                acc[i][j] = __builtin_amdgcn_mfma_f32_16x16x32_bf16(
                    af[i], bf[j], acc[i][j], 0, 0, 0);
    }

    // C/D layout (verified m89/m91): col=lane&15, row=(lane>>4)*4+reg
#pragma unroll
    for (int i = 0; i < 4; i++) {
        int gr = m0 + wm + i * 16 + kq * 4;
#pragma unroll
        for (int j = 0; j < 4; j++) {
            int gc = n0 + wn + j * 16 + lr;
            float bv = bias[gc];
#pragma unroll
            for (int r = 0; r < 4; r++) {
                float v = acc[i][j][r] + bv;
                if (TANH) v = tanhf(v);
                C[(size_t)(gr + r) * N + gc] = v;
            }
        }
    }
}

// dst[N,K] (bf16) = src[K,N]^T (fp32)
__global__ void transpose_k(const float* __restrict__ src, bf16_t* __restrict__ dst, int N) {
    __shared__ float t[32][33];
    int k0 = blockIdx.x * 32, n0 = blockIdx.y * 32;
    int tx = threadIdx.x & 31, ty = threadIdx.x >> 5;  // 256 thr: ty 0..7
#pragma unroll
    for (int i = 0; i < 32; i += 8)
        t[ty + i][tx] = src[(size_t)(k0 + ty + i) * N + n0 + tx];
    __syncthreads();
#pragma unroll
    for (int i = 0; i < 32; i += 8)
        dst[(size_t)(n0 + ty + i) * K_ + k0 + tx] = (bf16_t)t[tx][ty + i];
}

// fused[b, 0:256] = x[b,t,:]; fused[b, 256+u] = hsum[b,u]  (bf16 out)
__global__ void fused_build(const float* __restrict__ x, int t,
                            const float* __restrict__ hsum,
                            bf16_t* __restrict__ fused) {
    int idx = blockIdx.x * 256 + threadIdx.x;
    int b = idx / K_;
    int j = idx - b * K_;
    if (j < F_) {
        fused[idx] = (bf16_t)x[((size_t)b * T_ + t) * F_ + j];
    } else {
        fused[idx] = (bf16_t)hsum[(size_t)b * U_ + (j - F_)];
    }
}

// qin[b,0:256]=x_t; qin[b,256+u] = sum_m softmax_m(-(R[b,u,m]-LNT*m)^2) * hhat[b,u,m]
__global__ void rq_build(const float* __restrict__ x, int t,
                         const float* __restrict__ Rb,
                         const float* __restrict__ hhat,
                         bf16_t* __restrict__ qin) {
    int idx = blockIdx.x * 256 + threadIdx.x;
    int b = idx / K_;
    int j = idx - b * K_;
    if (j < F_) {
        qin[idx] = (bf16_t)x[((size_t)b * T_ + t) * F_ + j];
    } else {
        int u = j - F_;
        const float* rp = Rb + (size_t)b * NRS + u * M_;
        const float* hp = hhat + ((size_t)b * U_ + u) * M_;
        float z[M_], mx = -1e30f;
#pragma unroll
        for (int m = 0; m < M_; m++) {
            float d = rp[m] - m * LNT;
            z[m] = -d * d;
            mx = fmaxf(mx, z[m]);
        }
        float den = 0.f, num = 0.f;
#pragma unroll
        for (int m = 0; m < M_; m++) {
            float e = expf(z[m] - mx);
            den += e;
            num += e * hp[m];
        }
        qin[idx] = (bf16_t)(num / den);
    }
}

// s_ki softmax, state update, h-sum. idx = b*U_+u.
__global__ void update_k(const float* __restrict__ Sb,
                         const float* __restrict__ qk,
                         float* __restrict__ hhat,
                         float* __restrict__ hsum) {
    int idx = blockIdx.x * 256 + threadIdx.x;  // B_*U_
    const float* sp = Sb + (size_t)idx * 8;
    float* hp = hhat + (size_t)idx * 8;
    float q = qk[idx];
    float z[M_], mx = -1e30f;
#pragma unroll
    for (int m = 0; m < M_; m++) {
        float d = sp[m] - m * LNT;
        z[m] = -d * d;
        mx = fmaxf(mx, z[m]);
    }
    float den = 0.f;
    float e[M_];
#pragma unroll
    for (int m = 0; m < M_; m++) { e[m] = expf(z[m] - mx); den += e[m]; }
    float hs = 0.f;
#pragma unroll
    for (int m = 0; m < M_; m++) {
        float s = e[m] / den;
        float dec = expf(-0.04f / (m * LNT + 1e-7f));  // m=0 -> 0
        float hn = ((1.f - s) * hp[m] + s * q) * dec;
        hp[m] = hn;
        hs += hn;
    }
    hsum[idx] = hs;
}

// out[b,t,:] = hsum[b,:] @ Wout[512,3] + bout   (one wave per b), fp32 out
__global__ void out_k(const float* __restrict__ hsum,
                      const float* __restrict__ Wout,
                      const float* __restrict__ bout,
                      float* __restrict__ out, int t) {
    int b = blockIdx.x;
    int lane = threadIdx.x;  // 64
    float p0 = 0, p1 = 0, p2 = 0;
    for (int u = lane; u < U_; u += 64) {
        float h = hsum[(size_t)b * U_ + u];
        p0 += h * Wout[u * 3 + 0];
        p1 += h * Wout[u * 3 + 1];
        p2 += h * Wout[u * 3 + 2];
    }
    for (int off = 32; off; off >>= 1) {
        p0 += __shfl_down(p0, off, 64);
        p1 += __shfl_down(p1, off, 64);
        p2 += __shfl_down(p2, off, 64);
    }
    if (lane == 0) {
        size_t o = ((size_t)b * T_ + t) * 3;
        out[o + 0] = p0 + bout[0];
        out[o + 1] = p1 + bout[1];
        out[o + 2] = p2 + bout[2];
    }
}

extern "C" void kernel_launch(void* const* d_in, const int* in_sizes, int n_in,
                              void* d_out, int out_size, void* d_ws, size_t ws_size,
                              hipStream_t stream) {
    const float* x   = (const float*)d_in[0];
    const float* W_r = (const float*)d_in[1];
    const float* b_r = (const float*)d_in[2];
    const float* W_q = (const float*)d_in[3];
    const float* b_q = (const float*)d_in[4];
    const float* W_s = (const float*)d_in[5];
    const float* b_s = (const float*)d_in[6];
    const float* W_o = (const float*)d_in[7];
    const float* b_o = (const float*)d_in[8];
    float* out = (float*)d_out;   // reference output dtype is float32

    char* ws = (char*)d_ws;
    float* hhat = (float*)ws;  ws += (size_t)B_ * U_ * M_ * 4;   // 64 MB
    float* RS   = (float*)ws;  ws += (size_t)B_ * NRS * 4;       // 64 MB (R then S)
    float* qk   = (float*)ws;  ws += (size_t)B_ * U_ * 4;        // 8 MB
    float* hsum = (float*)ws;  ws += (size_t)B_ * U_ * 4;        // 8 MB
    bf16_t* fused = (bf16_t*)ws;  ws += (size_t)B_ * K_ * 2;     // 6 MB
    bf16_t* qin   = (bf16_t*)ws;  ws += (size_t)B_ * K_ * 2;     // 6 MB
    bf16_t* WrT = (bf16_t*)ws; ws += (size_t)NRS * K_ * 2;       // 6 MB
    bf16_t* WsT = (bf16_t*)ws; ws += (size_t)NRS * K_ * 2;       // 6 MB
    bf16_t* WqT = (bf16_t*)ws; ws += (size_t)U_  * K_ * 2;       // 0.75 MB

    hipMemsetAsync(hhat, 0, (size_t)B_ * U_ * M_ * 4, stream);
    hipMemsetAsync(hsum, 0, (size_t)B_ * U_ * 4, stream);
    transpose_k<<<dim3(K_ / 32, NRS / 32), 256, 0, stream>>>(W_r, WrT, NRS);
    transpose_k<<<dim3(K_ / 32, NRS / 32), 256, 0, stream>>>(W_s, WsT, NRS);
    transpose_k<<<dim3(K_ / 32, U_  / 32), 256, 0, stream>>>(W_q, WqT, U_);

    for (int t = 0; t < T_; t++) {
        fused_build<<<B_ * K_ / 256, 256, 0, stream>>>(x, t, hsum, fused);
        gemm_bt<0><<<dim3(32, 32), 256, 0, stream>>>(fused, WrT, b_r, RS, NRS);
        rq_build<<<B_ * K_ / 256, 256, 0, stream>>>(x, t, RS, hhat, qin);
        gemm_bt<0><<<dim3(32, 32), 256, 0, stream>>>(fused, WsT, b_s, RS, NRS);
        gemm_bt<1><<<dim3(32, 4), 256, 0, stream>>>(qin, WqT, b_q, qk, U_);
        update_k<<<B_ * U_ / 256, 256, 0, stream>>>(RS, qk, hhat, hsum);
        out_k<<<B_, 64, 0, stream>>>(hsum, W_o, b_o, out, t);
    }
}

// Round 6
// 2243.350 us; speedup vs baseline: 8.9470x; 1.2788x over previous
//
#include <hip/hip_runtime.h>
#include <hip/hip_bf16.h>
#include <math.h>

#define B_   4096
#define T_   16
#define F_   256
#define U_   512
#define M_   8
#define K_   768    // F+U
#define NRS  4096   // U*M
#define NC   8192   // combined R|S output cols
#define LNT  1.1512925f  // 0.5*ln(10)

typedef __bf16 bf16_t;
typedef bf16_t bf16x8 __attribute__((ext_vector_type(8)));
typedef bf16_t bf16x4 __attribute__((ext_vector_type(4)));
typedef float  f32x4  __attribute__((ext_vector_type(4)));

__device__ inline void gl_lds16(const void* g, void* lds) {
    __builtin_amdgcn_global_load_lds(
        (const __attribute__((address_space(1))) unsigned int*)g,
        (__attribute__((address_space(3))) unsigned int*)lds, 16, 0, 0);
}

// ---------------------------------------------------------------------------
// Combined R|S GEMM with fused softmax epilogue.
// C = fused[B_,K_] @ WrsT[NC,K_]^T + biasP. Columns within each 64-group are
// PERMUTED: physical (j,lr) holds logical col (lr&7)*8 + (lr>>3)*4 + j, so a
// lane's 4 j-regs are 4 consecutive m's of one u; partner lane is lane^8.
// R half (n<4096): r_ki softmax -> rh = sum_m r*hhat -> qin h-part (bf16).
// S half: s_ki softmax stored bf16 to sbuf.
// ---------------------------------------------------------------------------
__global__ __launch_bounds__(256) void gemm_rs_ep(
    const bf16_t* __restrict__ A,      // fused [B_][K_]
    const bf16_t* __restrict__ Bt,     // WrsT [NC][K_] (perm)
    const float*  __restrict__ biasP,  // [NC] (perm)
    const bf16_t* __restrict__ hhat,   // [B_][NRS]
    bf16_t* __restrict__ qin,          // [B_][K_] (h-part written)
    bf16_t* __restrict__ sbuf)         // [B_][NRS]
{
    __shared__ bf16_t Al[128 * 32];
    __shared__ bf16_t Bl[128 * 32];

    const int tid  = threadIdx.x;
    const int lane = tid & 63;
    const int wave = tid >> 6;
    const int m0 = blockIdx.x * 128;
    const int n0 = blockIdx.y * 128;
    const int wm = (wave & 1) * 64;
    const int wn = (wave >> 1) * 64;
    const int lr = lane & 15;
    const int kq = lane >> 4;

    f32x4 acc[4][4] = {};

    const int c0 = tid, c1 = tid + 256;
    const int r0 = c0 >> 2, kc0 = (c0 & 3) * 8;
    const int r1 = c1 >> 2, kc1 = (c1 & 3) * 8;

    for (int kk = 0; kk < K_; kk += 32) {
        __syncthreads();
        gl_lds16(A  + (size_t)(m0 + r0) * K_ + kk + kc0, (char*)Al + c0 * 16);
        gl_lds16(A  + (size_t)(m0 + r1) * K_ + kk + kc1, (char*)Al + c1 * 16);
        gl_lds16(Bt + (size_t)(n0 + r0) * K_ + kk + kc0, (char*)Bl + c0 * 16);
        gl_lds16(Bt + (size_t)(n0 + r1) * K_ + kk + kc1, (char*)Bl + c1 * 16);
        __syncthreads();

        bf16x8 af[4], bfr[4];
#pragma unroll
        for (int i = 0; i < 4; i++)
            af[i] = *(const bf16x8*)(Al + (wm + i * 16 + lr) * 32 + kq * 8);
#pragma unroll
        for (int i = 0; i < 4; i++)
            bfr[i] = *(const bf16x8*)(Bl + (wn + i * 16 + lr) * 32 + kq * 8);
#pragma unroll
        for (int i = 0; i < 4; i++)
#pragma unroll
            for (int j = 0; j < 4; j++)
                acc[i][j] = __builtin_amdgcn_mfma_f32_16x16x32_bf16(
                    af[i], bfr[j], acc[i][j], 0, 0, 0);
    }

    // epilogue: C/D layout col(physical)=lane&15, row=(lane>>4)*4+reg
    const int nb  = n0 + wn;            // 64-aligned group base (phys==logical)
    const int u3  = lane & 7;           // u within group
    const int m0v = ((lane >> 3) & 1) * 4;  // this lane's m-offset (0 or 4)
    const bool is_r = nb < NRS;

    float bj[4];
#pragma unroll
    for (int j = 0; j < 4; j++) bj[j] = biasP[nb + j * 16 + lr];

#pragma unroll
    for (int i = 0; i < 4; i++) {
        const int rowb = m0 + wm + i * 16 + kq * 4;
#pragma unroll
        for (int r = 0; r < 4; r++) {
            const int row = rowb + r;
            float z[4], mx = -1e30f;
#pragma unroll
            for (int j = 0; j < 4; j++) {
                float v = acc[i][j][r] + bj[j];
                float d = v - (float)(m0v + j) * LNT;
                z[j] = -d * d;
                mx = fmaxf(mx, z[j]);
            }
            mx = fmaxf(mx, __shfl_xor(mx, 8, 64));
            float e[4], sum = 0.f;
#pragma unroll
            for (int j = 0; j < 4; j++) { e[j] = __expf(z[j] - mx); sum += e[j]; }
            sum += __shfl_xor(sum, 8, 64);
            const float inv = 1.0f / sum;
            if (is_r) {
                bf16x4 h4 = *(const bf16x4*)(hhat + (size_t)row * NRS + nb + u3 * 8 + m0v);
                float rh = 0.f;
#pragma unroll
                for (int j = 0; j < 4; j++) rh += e[j] * inv * (float)h4[j];
                rh += __shfl_xor(rh, 8, 64);
                if ((lane & 8) == 0)
                    qin[(size_t)row * K_ + F_ + (nb >> 3) + u3] = (bf16_t)rh;
            } else {
                bf16x4 pv;
#pragma unroll
                for (int j = 0; j < 4; j++) pv[j] = (bf16_t)(e[j] * inv);
                *(bf16x4*)(sbuf + (size_t)row * NRS + (nb - NRS) + u3 * 8 + m0v) = pv;
            }
        }
    }
}

// ---------------------------------------------------------------------------
// q GEMM + fused state update. C = qin @ WqT^T + b_q -> tanh -> q.
// Epilogue: read s_ki,hhat (bf16x8), h_next=((1-s)h+s q)*DEC, write hhat and
// the NEXT step's fused h-part (= this step's hidden output).
// ---------------------------------------------------------------------------
__global__ __launch_bounds__(256) void gemm_q_up(
    const bf16_t* __restrict__ A,      // qin
    const bf16_t* __restrict__ Bt,     // WqT [U_][K_]
    const float*  __restrict__ bq,
    const bf16_t* __restrict__ sbuf,
    bf16_t* __restrict__ hhat,
    bf16_t* __restrict__ fused)
{
    __shared__ bf16_t Al[128 * 32];
    __shared__ bf16_t Bl[128 * 32];

    const int tid  = threadIdx.x;
    const int lane = tid & 63;
    const int wave = tid >> 6;
    const int m0 = blockIdx.x * 128;
    const int n0 = blockIdx.y * 128;
    const int wm = (wave & 1) * 64;
    const int wn = (wave >> 1) * 64;
    const int lr = lane & 15;
    const int kq = lane >> 4;

    f32x4 acc[4][4] = {};

    const int c0 = tid, c1 = tid + 256;
    const int r0 = c0 >> 2, kc0 = (c0 & 3) * 8;
    const int r1 = c1 >> 2, kc1 = (c1 & 3) * 8;

    for (int kk = 0; kk < K_; kk += 32) {
        __syncthreads();
        gl_lds16(A  + (size_t)(m0 + r0) * K_ + kk + kc0, (char*)Al + c0 * 16);
        gl_lds16(A  + (size_t)(m0 + r1) * K_ + kk + kc1, (char*)Al + c1 * 16);
        gl_lds16(Bt + (size_t)(n0 + r0) * K_ + kk + kc0, (char*)Bl + c0 * 16);
        gl_lds16(Bt + (size_t)(n0 + r1) * K_ + kk + kc1, (char*)Bl + c1 * 16);
        __syncthreads();

        bf16x8 af[4], bfr[4];
#pragma unroll
        for (int i = 0; i < 4; i++)
            af[i] = *(const bf16x8*)(Al + (wm + i * 16 + lr) * 32 + kq * 8);
#pragma unroll
        for (int i = 0; i < 4; i++)
            bfr[i] = *(const bf16x8*)(Bl + (wn + i * 16 + lr) * 32 + kq * 8);
#pragma unroll
        for (int i = 0; i < 4; i++)
#pragma unroll
            for (int j = 0; j < 4; j++)
                acc[i][j] = __builtin_amdgcn_mfma_f32_16x16x32_bf16(
                    af[i], bfr[j], acc[i][j], 0, 0, 0);
    }

    const float DEC[8] = {0.0f, 0.9658531f, 0.9827783f, 0.9884856f,
                          0.9913518f, 0.9930754f, 0.9942261f, 0.9950489f};

#pragma unroll
    for (int i = 0; i < 4; i++) {
        const int rowb = m0 + wm + i * 16 + kq * 4;
#pragma unroll
        for (int j = 0; j < 4; j++) {
            const int u = n0 + wn + j * 16 + lr;
            const float bv = bq[u];
#pragma unroll
            for (int r = 0; r < 4; r++) {
                const int row = rowb + r;
                const float q = tanhf(acc[i][j][r] + bv);
                const size_t base = (size_t)row * NRS + u * 8;
                bf16x8 s8 = *(const bf16x8*)(sbuf + base);
                bf16x8 h8 = *(const bf16x8*)(hhat + base);
                bf16x8 ho;
                float hs = 0.f;
#pragma unroll
                for (int m = 0; m < 8; m++) {
                    float s = (float)s8[m];
                    float h = (float)h8[m];
                    float hn = ((1.f - s) * h + s * q) * DEC[m];
                    ho[m] = (bf16_t)hn;
                    hs += hn;
                }
                *(bf16x8*)(hhat + base) = ho;
                fused[(size_t)row * K_ + F_ + u] = (bf16_t)hs;
            }
        }
    }
}

// dst[p][K_] = bf16(src[K_][NRS] col L), rows permuted within 64-groups.
__global__ void transpose_perm(const float* __restrict__ src, bf16_t* __restrict__ dst) {
    __shared__ float tl[32][33];
    int k0 = blockIdx.x * 32, n0 = blockIdx.y * 32;
    int tx = threadIdx.x & 31, ty = threadIdx.x >> 5;
#pragma unroll
    for (int i = 0; i < 32; i += 8)
        tl[ty + i][tx] = src[(size_t)(k0 + ty + i) * NRS + n0 + tx];
    __syncthreads();
#pragma unroll
    for (int i = 0; i < 32; i += 8) {
        int n = n0 + ty + i;
        int m = n & 7, u3v = (n >> 3) & 7;
        int p = (n & ~63) + (m & 3) * 16 + (m >> 2) * 8 + u3v;
        dst[(size_t)p * K_ + k0 + tx] = (bf16_t)tl[tx][ty + i];
    }
}

// plain transpose: dst[N][K_] = bf16(src[K_][N]^T)
__global__ void transpose_plain(const float* __restrict__ src, bf16_t* __restrict__ dst, int N) {
    __shared__ float tl[32][33];
    int k0 = blockIdx.x * 32, n0 = blockIdx.y * 32;
    int tx = threadIdx.x & 31, ty = threadIdx.x >> 5;
#pragma unroll
    for (int i = 0; i < 32; i += 8)
        tl[ty + i][tx] = src[(size_t)(k0 + ty + i) * N + n0 + tx];
    __syncthreads();
#pragma unroll
    for (int i = 0; i < 32; i += 8)
        dst[(size_t)(n0 + ty + i) * K_ + k0 + tx] = (bf16_t)tl[tx][ty + i];
}

__global__ void bias_perm(const float* __restrict__ b_r, const float* __restrict__ b_s,
                          float* __restrict__ biasP) {
    int p = blockIdx.x * 256 + threadIdx.x;  // NC
    int pr = p & 63, j = pr >> 4, lr = pr & 15;
    int L = (p & ~63) + (lr & 7) * 8 + ((lr >> 3) & 1) * 4 + j;
    biasP[p] = (L < NRS) ? b_r[L] : b_s[L - NRS];
}

__global__ void xcopy(const float* __restrict__ x, int t,
                      bf16_t* __restrict__ fused, bf16_t* __restrict__ qin) {
    int b = blockIdx.x, f = threadIdx.x;  // 256 = F_
    float v = x[((size_t)b * T_ + t) * F_ + f];
    fused[(size_t)b * K_ + f] = (bf16_t)v;
    qin[(size_t)b * K_ + f] = (bf16_t)v;
}

__global__ void init_h(bf16_t* __restrict__ fused) {
    int idx = blockIdx.x * 256 + threadIdx.x;  // B_*U_
    int b = idx >> 9, u = idx & 511;
    fused[(size_t)b * K_ + F_ + u] = (bf16_t)0.f;
}

// out[b,t,:] = h(t)[b,:] @ Wout + bout; h read bf16 from fused h-part.
__global__ void out_k(const bf16_t* __restrict__ fused,
                      const float* __restrict__ Wout,
                      const float* __restrict__ bout,
                      float* __restrict__ out, int t) {
    int b = blockIdx.x;
    int lane = threadIdx.x;  // 64
    float p0 = 0, p1 = 0, p2 = 0;
    for (int u = lane; u < U_; u += 64) {
        float h = (float)fused[(size_t)b * K_ + F_ + u];
        p0 += h * Wout[u * 3 + 0];
        p1 += h * Wout[u * 3 + 1];
        p2 += h * Wout[u * 3 + 2];
    }
    for (int off = 32; off; off >>= 1) {
        p0 += __shfl_down(p0, off, 64);
        p1 += __shfl_down(p1, off, 64);
        p2 += __shfl_down(p2, off, 64);
    }
    if (lane == 0) {
        size_t o = ((size_t)b * T_ + t) * 3;
        out[o + 0] = p0 + bout[0];
        out[o + 1] = p1 + bout[1];
        out[o + 2] = p2 + bout[2];
    }
}

extern "C" void kernel_launch(void* const* d_in, const int* in_sizes, int n_in,
                              void* d_out, int out_size, void* d_ws, size_t ws_size,
                              hipStream_t stream) {
    const float* x   = (const float*)d_in[0];
    const float* W_r = (const float*)d_in[1];
    const float* b_r = (const float*)d_in[2];
    const float* W_q = (const float*)d_in[3];
    const float* b_q = (const float*)d_in[4];
    const float* W_s = (const float*)d_in[5];
    const float* b_s = (const float*)d_in[6];
    const float* W_o = (const float*)d_in[7];
    const float* b_o = (const float*)d_in[8];
    float* out = (float*)d_out;

    char* ws = (char*)d_ws;
    bf16_t* hhat  = (bf16_t*)ws; ws += (size_t)B_ * NRS * 2;   // 32 MB
    bf16_t* sbuf  = (bf16_t*)ws; ws += (size_t)B_ * NRS * 2;   // 32 MB
    bf16_t* fused = (bf16_t*)ws; ws += (size_t)B_ * K_ * 2;    // 6 MB
    bf16_t* qin   = (bf16_t*)ws; ws += (size_t)B_ * K_ * 2;    // 6 MB
    bf16_t* WrsT  = (bf16_t*)ws; ws += (size_t)NC * K_ * 2;    // 12 MB
    bf16_t* WqT   = (bf16_t*)ws; ws += (size_t)U_ * K_ * 2;    // 0.75 MB
    float*  biasP = (float*)ws;  ws += (size_t)NC * 4;         // 32 KB

    hipMemsetAsync(hhat, 0, (size_t)B_ * NRS * 2, stream);
    transpose_perm<<<dim3(K_ / 32, NRS / 32), 256, 0, stream>>>(W_r, WrsT);
    transpose_perm<<<dim3(K_ / 32, NRS / 32), 256, 0, stream>>>(W_s, WrsT + (size_t)NRS * K_);
    transpose_plain<<<dim3(K_ / 32, U_ / 32), 256, 0, stream>>>(W_q, WqT, U_);
    bias_perm<<<NC / 256, 256, 0, stream>>>(b_r, b_s, biasP);
    init_h<<<B_ * U_ / 256, 256, 0, stream>>>(fused);

    for (int t = 0; t < T_; t++) {
        xcopy<<<B_, F_, 0, stream>>>(x, t, fused, qin);
        gemm_rs_ep<<<dim3(32, 64), 256, 0, stream>>>(fused, WrsT, biasP, hhat, qin, sbuf);
        gemm_q_up<<<dim3(32, 4), 256, 0, stream>>>(qin, WqT, b_q, sbuf, hhat, fused);
        out_k<<<B_, 64, 0, stream>>>(fused, W_o, b_o, out, t);
    }
}

// Round 7
// 1917.845 us; speedup vs baseline: 10.4655x; 1.1697x over previous
//
#include <hip/hip_runtime.h>
#include <hip/hip_bf16.h>
#include <math.h>

#define B_   4096
#define T_   16
#define F_   256
#define U_   512
#define M_   8
#define K_   768    // F+U
#define NRS  4096   // U*M
#define NC   8192   // combined R|S output cols
#define LNT  1.1512925f  // 0.5*ln(10)

typedef __bf16 bf16_t;
typedef bf16_t bf16x8 __attribute__((ext_vector_type(8)));
typedef bf16_t bf16x4 __attribute__((ext_vector_type(4)));
typedef float  f32x4  __attribute__((ext_vector_type(4)));

__device__ inline void gl_lds16(const void* g, void* lds) {
    __builtin_amdgcn_global_load_lds(
        (const __attribute__((address_space(1))) unsigned int*)g,
        (__attribute__((address_space(3))) unsigned int*)lds, 16, 0, 0);
}

// ---------------------------------------------------------------------------
// Combined R|S GEMM with fused softmax epilogue. A is split: cols [0,256) from
// xt[B_][F_], cols [256,768) from hprev[B_][U_] (uniform per-K-tile select).
// Weight columns permuted within 64-groups (see transpose_perm): a lane's 4
// j-regs hold 4 consecutive m's of one u; partner lane = lane^8.
// R half (n<4096): softmax -> rh = sum_m r*hhat -> rh[B_][U_] (bf16).
// S half: softmax stored bf16 to sbuf.
// ---------------------------------------------------------------------------
__global__ __launch_bounds__(256) void gemm_rs_ep(
    const bf16_t* __restrict__ xt,     // [B_][F_]  x at step t
    const bf16_t* __restrict__ hprev,  // [B_][U_]
    const bf16_t* __restrict__ Bt,     // WrsT [NC][K_] (perm)
    const float*  __restrict__ biasP,  // [NC] (perm)
    const bf16_t* __restrict__ hhat,   // [B_][NRS]
    bf16_t* __restrict__ rh,           // [B_][U_]
    bf16_t* __restrict__ sbuf)         // [B_][NRS]
{
    __shared__ bf16_t Al[128 * 32];
    __shared__ bf16_t Bl[128 * 32];

    const int tid  = threadIdx.x;
    const int lane = tid & 63;
    const int wave = tid >> 6;
    const int m0 = blockIdx.x * 128;
    const int n0 = blockIdx.y * 128;
    const int wm = (wave & 1) * 64;
    const int wn = (wave >> 1) * 64;
    const int lr = lane & 15;
    const int kq = lane >> 4;

    f32x4 acc[4][4] = {};

    const int c0 = tid, c1 = tid + 256;
    const int r0 = c0 >> 2, kc0 = (c0 & 3) * 8;
    const int r1 = c1 >> 2, kc1 = (c1 & 3) * 8;

    for (int kk = 0; kk < K_; kk += 32) {
        const bf16_t* a0 = (kk < F_)
            ? xt    + (size_t)(m0 + r0) * F_ + kk + kc0
            : hprev + (size_t)(m0 + r0) * U_ + (kk - F_) + kc0;
        const bf16_t* a1 = (kk < F_)
            ? xt    + (size_t)(m0 + r1) * F_ + kk + kc1
            : hprev + (size_t)(m0 + r1) * U_ + (kk - F_) + kc1;
        __syncthreads();
        gl_lds16(a0, (char*)Al + c0 * 16);
        gl_lds16(a1, (char*)Al + c1 * 16);
        gl_lds16(Bt + (size_t)(n0 + r0) * K_ + kk + kc0, (char*)Bl + c0 * 16);
        gl_lds16(Bt + (size_t)(n0 + r1) * K_ + kk + kc1, (char*)Bl + c1 * 16);
        __syncthreads();

        bf16x8 af[4], bfr[4];
#pragma unroll
        for (int i = 0; i < 4; i++)
            af[i] = *(const bf16x8*)(Al + (wm + i * 16 + lr) * 32 + kq * 8);
#pragma unroll
        for (int i = 0; i < 4; i++)
            bfr[i] = *(const bf16x8*)(Bl + (wn + i * 16 + lr) * 32 + kq * 8);
#pragma unroll
        for (int i = 0; i < 4; i++)
#pragma unroll
            for (int j = 0; j < 4; j++)
                acc[i][j] = __builtin_amdgcn_mfma_f32_16x16x32_bf16(
                    af[i], bfr[j], acc[i][j], 0, 0, 0);
    }

    const int nb  = n0 + wn;
    const int u3  = lane & 7;
    const int m0v = ((lane >> 3) & 1) * 4;
    const bool is_r = nb < NRS;

    float bj[4];
#pragma unroll
    for (int j = 0; j < 4; j++) bj[j] = biasP[nb + j * 16 + lr];

#pragma unroll
    for (int i = 0; i < 4; i++) {
        const int rowb = m0 + wm + i * 16 + kq * 4;
#pragma unroll
        for (int r = 0; r < 4; r++) {
            const int row = rowb + r;
            float z[4], mx = -1e30f;
#pragma unroll
            for (int j = 0; j < 4; j++) {
                float v = acc[i][j][r] + bj[j];
                float d = v - (float)(m0v + j) * LNT;
                z[j] = -d * d;
                mx = fmaxf(mx, z[j]);
            }
            mx = fmaxf(mx, __shfl_xor(mx, 8, 64));
            float e[4], sum = 0.f;
#pragma unroll
            for (int j = 0; j < 4; j++) { e[j] = __expf(z[j] - mx); sum += e[j]; }
            sum += __shfl_xor(sum, 8, 64);
            const float inv = 1.0f / sum;
            if (is_r) {
                bf16x4 h4 = *(const bf16x4*)(hhat + (size_t)row * NRS + nb + u3 * 8 + m0v);
                float rhv = 0.f;
#pragma unroll
                for (int j = 0; j < 4; j++) rhv += e[j] * inv * (float)h4[j];
                rhv += __shfl_xor(rhv, 8, 64);
                if ((lane & 8) == 0)
                    rh[(size_t)row * U_ + (nb >> 3) + u3] = (bf16_t)rhv;
            } else {
                bf16x4 pv;
#pragma unroll
                for (int j = 0; j < 4; j++) pv[j] = (bf16_t)(e[j] * inv);
                *(bf16x4*)(sbuf + (size_t)row * NRS + (nb - NRS) + u3 * 8 + m0v) = pv;
            }
        }
    }
}

// ---------------------------------------------------------------------------
// q GEMM (64x64 tiles for occupancy: grid 64x8=512 blocks) + fused state
// update. A split: x | rh. C -> tanh -> q; h_next=((1-s)h+s q)*DEC -> hhat,
// hnext (= hidden output of this step).
// ---------------------------------------------------------------------------
__global__ __launch_bounds__(256) void gemm_q_up(
    const bf16_t* __restrict__ xt,     // [B_][F_]
    const bf16_t* __restrict__ rh,     // [B_][U_]
    const bf16_t* __restrict__ Bt,     // WqT [U_][K_]
    const float*  __restrict__ bq,
    const bf16_t* __restrict__ sbuf,
    bf16_t* __restrict__ hhat,
    bf16_t* __restrict__ hnext)        // [B_][U_]
{
    __shared__ bf16_t Al[64 * 32];
    __shared__ bf16_t Bl[64 * 32];

    const int tid  = threadIdx.x;
    const int lane = tid & 63;
    const int wave = tid >> 6;
    const int m0 = blockIdx.x * 64;
    const int n0 = blockIdx.y * 64;
    const int wm = (wave & 1) * 32;
    const int wn = (wave >> 1) * 32;
    const int lr = lane & 15;
    const int kq = lane >> 4;

    f32x4 acc[2][2] = {};

    const int r0 = tid >> 2, kc0 = (tid & 3) * 8;  // 256 chunks = whole 64x32 tile

    for (int kk = 0; kk < K_; kk += 32) {
        const bf16_t* a0 = (kk < F_)
            ? xt + (size_t)(m0 + r0) * F_ + kk + kc0
            : rh + (size_t)(m0 + r0) * U_ + (kk - F_) + kc0;
        __syncthreads();
        gl_lds16(a0, (char*)Al + tid * 16);
        gl_lds16(Bt + (size_t)(n0 + r0) * K_ + kk + kc0, (char*)Bl + tid * 16);
        __syncthreads();

        bf16x8 af[2], bfr[2];
#pragma unroll
        for (int i = 0; i < 2; i++)
            af[i] = *(const bf16x8*)(Al + (wm + i * 16 + lr) * 32 + kq * 8);
#pragma unroll
        for (int i = 0; i < 2; i++)
            bfr[i] = *(const bf16x8*)(Bl + (wn + i * 16 + lr) * 32 + kq * 8);
#pragma unroll
        for (int i = 0; i < 2; i++)
#pragma unroll
            for (int j = 0; j < 2; j++)
                acc[i][j] = __builtin_amdgcn_mfma_f32_16x16x32_bf16(
                    af[i], bfr[j], acc[i][j], 0, 0, 0);
    }

    const float DEC[8] = {0.0f, 0.9658531f, 0.9827783f, 0.9884856f,
                          0.9913518f, 0.9930754f, 0.9942261f, 0.9950489f};

#pragma unroll
    for (int i = 0; i < 2; i++) {
        const int rowb = m0 + wm + i * 16 + kq * 4;
#pragma unroll
        for (int j = 0; j < 2; j++) {
            const int u = n0 + wn + j * 16 + lr;
            const float bv = bq[u];
#pragma unroll
            for (int r = 0; r < 4; r++) {
                const int row = rowb + r;
                const float q = tanhf(acc[i][j][r] + bv);
                const size_t base = (size_t)row * NRS + u * 8;
                bf16x8 s8 = *(const bf16x8*)(sbuf + base);
                bf16x8 h8 = *(const bf16x8*)(hhat + base);
                bf16x8 ho;
                float hs = 0.f;
#pragma unroll
                for (int m = 0; m < 8; m++) {
                    float s = (float)s8[m];
                    float h = (float)h8[m];
                    float hn = ((1.f - s) * h + s * q) * DEC[m];
                    ho[m] = (bf16_t)hn;
                    hs += hn;
                }
                *(bf16x8*)(hhat + base) = ho;
                hnext[(size_t)row * U_ + u] = (bf16_t)hs;
            }
        }
    }
}

// dst[p][K_] = bf16(src[K_][NRS] col L), rows permuted within 64-groups.
__global__ void transpose_perm(const float* __restrict__ src, bf16_t* __restrict__ dst) {
    __shared__ float tl[32][33];
    int k0 = blockIdx.x * 32, n0 = blockIdx.y * 32;
    int tx = threadIdx.x & 31, ty = threadIdx.x >> 5;
#pragma unroll
    for (int i = 0; i < 32; i += 8)
        tl[ty + i][tx] = src[(size_t)(k0 + ty + i) * NRS + n0 + tx];
    __syncthreads();
#pragma unroll
    for (int i = 0; i < 32; i += 8) {
        int n = n0 + ty + i;
        int m = n & 7, u3v = (n >> 3) & 7;
        int p = (n & ~63) + (m & 3) * 16 + (m >> 2) * 8 + u3v;
        dst[(size_t)p * K_ + k0 + tx] = (bf16_t)tl[tx][ty + i];
    }
}

// plain transpose: dst[N][K_] = bf16(src[K_][N]^T)
__global__ void transpose_plain(const float* __restrict__ src, bf16_t* __restrict__ dst, int N) {
    __shared__ float tl[32][33];
    int k0 = blockIdx.x * 32, n0 = blockIdx.y * 32;
    int tx = threadIdx.x & 31, ty = threadIdx.x >> 5;
#pragma unroll
    for (int i = 0; i < 32; i += 8)
        tl[ty + i][tx] = src[(size_t)(k0 + ty + i) * N + n0 + tx];
    __syncthreads();
#pragma unroll
    for (int i = 0; i < 32; i += 8)
        dst[(size_t)(n0 + ty + i) * K_ + k0 + tx] = (bf16_t)tl[tx][ty + i];
}

__global__ void bias_perm(const float* __restrict__ b_r, const float* __restrict__ b_s,
                          float* __restrict__ biasP) {
    int p = blockIdx.x * 256 + threadIdx.x;  // NC
    int pr = p & 63, j = pr >> 4, lr = pr & 15;
    int L = (p & ~63) + (lr & 7) * 8 + ((lr >> 3) & 1) * 4 + j;
    biasP[p] = (L < NRS) ? b_r[L] : b_s[L - NRS];
}

// xall[t][b][f] = bf16(x[b][t][f])
__global__ void xall_build(const float* __restrict__ x, bf16_t* __restrict__ xall) {
    int idx = blockIdx.x * 256 + threadIdx.x;  // B_*T_*F_ = 16M
    int b = idx >> 12;            // / (T_*F_)
    int rem = idx & 4095;
    int t = rem >> 8, f = rem & 255;
    xall[((size_t)t * B_ + b) * F_ + f] = (bf16_t)x[idx];
}

// out[b,t,:] = hnext[b,:] @ Wout + bout
__global__ void out_k(const bf16_t* __restrict__ hnext,
                      const float* __restrict__ Wout,
                      const float* __restrict__ bout,
                      float* __restrict__ out, int t) {
    int b = blockIdx.x;
    int lane = threadIdx.x;  // 64
    float p0 = 0, p1 = 0, p2 = 0;
    for (int u = lane; u < U_; u += 64) {
        float h = (float)hnext[(size_t)b * U_ + u];
        p0 += h * Wout[u * 3 + 0];
        p1 += h * Wout[u * 3 + 1];
        p2 += h * Wout[u * 3 + 2];
    }
    for (int off = 32; off; off >>= 1) {
        p0 += __shfl_down(p0, off, 64);
        p1 += __shfl_down(p1, off, 64);
        p2 += __shfl_down(p2, off, 64);
    }
    if (lane == 0) {
        size_t o = ((size_t)b * T_ + t) * 3;
        out[o + 0] = p0 + bout[0];
        out[o + 1] = p1 + bout[1];
        out[o + 2] = p2 + bout[2];
    }
}

extern "C" void kernel_launch(void* const* d_in, const int* in_sizes, int n_in,
                              void* d_out, int out_size, void* d_ws, size_t ws_size,
                              hipStream_t stream) {
    const float* x   = (const float*)d_in[0];
    const float* W_r = (const float*)d_in[1];
    const float* b_r = (const float*)d_in[2];
    const float* W_q = (const float*)d_in[3];
    const float* b_q = (const float*)d_in[4];
    const float* W_s = (const float*)d_in[5];
    const float* b_s = (const float*)d_in[6];
    const float* W_o = (const float*)d_in[7];
    const float* b_o = (const float*)d_in[8];
    float* out = (float*)d_out;

    char* ws = (char*)d_ws;
    bf16_t* hhat  = (bf16_t*)ws; ws += (size_t)B_ * NRS * 2;   // 32 MB
    bf16_t* sbuf  = (bf16_t*)ws; ws += (size_t)B_ * NRS * 2;   // 32 MB
    bf16_t* xall  = (bf16_t*)ws; ws += (size_t)B_ * T_ * F_ * 2; // 32 MB
    bf16_t* hA    = (bf16_t*)ws; ws += (size_t)B_ * U_ * 2;    // 4 MB
    bf16_t* hB    = (bf16_t*)ws; ws += (size_t)B_ * U_ * 2;    // 4 MB
    bf16_t* rh    = (bf16_t*)ws; ws += (size_t)B_ * U_ * 2;    // 4 MB
    bf16_t* WrsT  = (bf16_t*)ws; ws += (size_t)NC * K_ * 2;    // 12 MB
    bf16_t* WqT   = (bf16_t*)ws; ws += (size_t)U_ * K_ * 2;    // 0.75 MB
    float*  biasP = (float*)ws;  ws += (size_t)NC * 4;         // 32 KB

    hipMemsetAsync(hhat, 0, (size_t)B_ * NRS * 2, stream);
    hipMemsetAsync(hA, 0, (size_t)B_ * U_ * 2, stream);
    xall_build<<<B_ * T_ * F_ / 256, 256, 0, stream>>>(x, xall);
    transpose_perm<<<dim3(K_ / 32, NRS / 32), 256, 0, stream>>>(W_r, WrsT);
    transpose_perm<<<dim3(K_ / 32, NRS / 32), 256, 0, stream>>>(W_s, WrsT + (size_t)NRS * K_);
    transpose_plain<<<dim3(K_ / 32, U_ / 32), 256, 0, stream>>>(W_q, WqT, U_);
    bias_perm<<<NC / 256, 256, 0, stream>>>(b_r, b_s, biasP);

    for (int t = 0; t < T_; t++) {
        const bf16_t* xt = xall + (size_t)t * B_ * F_;
        const bf16_t* hp = (t & 1) ? hB : hA;
        bf16_t*       hn = (t & 1) ? hA : hB;
        gemm_rs_ep<<<dim3(32, 64), 256, 0, stream>>>(xt, hp, WrsT, biasP, hhat, rh, sbuf);
        gemm_q_up<<<dim3(64, 8), 256, 0, stream>>>(xt, rh, WqT, b_q, sbuf, hhat, hn);
        out_k<<<B_, 64, 0, stream>>>(hn, W_o, b_o, out, t);
    }
}

// Round 8
// 1742.502 us; speedup vs baseline: 11.5186x; 1.1006x over previous
//
#include <hip/hip_runtime.h>
#include <hip/hip_bf16.h>
#include <math.h>

#define B_   4096
#define T_   16
#define F_   256
#define U_   512
#define M_   8
#define K_   768    // F+U
#define NRS  4096   // U*M
#define NC   8192   // combined R|S output cols
#define LNT  1.1512925f  // 0.5*ln(10)

typedef __bf16 bf16_t;
typedef bf16_t bf16x8 __attribute__((ext_vector_type(8)));
typedef bf16_t bf16x4 __attribute__((ext_vector_type(4)));
typedef float  f32x4  __attribute__((ext_vector_type(4)));

__device__ inline void gl_lds16(const void* g, void* lds) {
    __builtin_amdgcn_global_load_lds(
        (const __attribute__((address_space(1))) unsigned int*)g,
        (__attribute__((address_space(3))) unsigned int*)lds, 16, 0, 0);
}

// ---------------------------------------------------------------------------
// Combined R|S GEMM with fused softmax epilogue. BK=64 staged as two 32-col
// sub-tiles (keeps the conflict-free stride-64B LDS rows; global_load_lds
// forbids padding). 12 barrier-pairs instead of 24.
// A split: cols [0,256) from xt, cols [256,768) from hprev (uniform select;
// 64-col tiles never straddle the boundary since F_=256 is a multiple of 64).
// Weight cols permuted within 64-groups: lane's 4 j-regs = 4 consecutive m's
// of one u; partner lane = lane^8.
// ---------------------------------------------------------------------------
__global__ __launch_bounds__(256) void gemm_rs_ep(
    const bf16_t* __restrict__ xt,     // [B_][F_]
    const bf16_t* __restrict__ hprev,  // [B_][U_]
    const bf16_t* __restrict__ Bt,     // WrsT [NC][K_] (perm)
    const float*  __restrict__ biasP,  // [NC] (perm)
    const bf16_t* __restrict__ hhat,   // [B_][NRS]
    bf16_t* __restrict__ rh,           // [B_][U_]
    bf16_t* __restrict__ sbuf)         // [B_][NRS]
{
    __shared__ bf16_t Al[2][128 * 32];
    __shared__ bf16_t Bl[2][128 * 32];

    const int tid  = threadIdx.x;
    const int lane = tid & 63;
    const int wave = tid >> 6;
    const int m0 = blockIdx.x * 128;
    const int n0 = blockIdx.y * 128;
    const int wm = (wave & 1) * 64;
    const int wn = (wave >> 1) * 64;
    const int lr = lane & 15;
    const int kq = lane >> 4;

    f32x4 acc[4][4] = {};

    const int rA0 = tid >> 2, rA1 = 64 + (tid >> 2);
    const int kc  = (tid & 3) * 8;

    for (int kk = 0; kk < K_; kk += 64) {
        // uniform per-tile A source select (x vs h); both sub-tiles same side
        const bf16_t* arow0;
        const bf16_t* arow1;
        int cbase;
        if (kk < F_) { arow0 = xt + (size_t)(m0 + rA0) * F_;
                       arow1 = xt + (size_t)(m0 + rA1) * F_; cbase = kk; }
        else         { arow0 = hprev + (size_t)(m0 + rA0) * U_;
                       arow1 = hprev + (size_t)(m0 + rA1) * U_; cbase = kk - F_; }

        __syncthreads();
        gl_lds16(arow0 + cbase + kc,      (char*)&Al[0][0] + tid * 16);
        gl_lds16(arow1 + cbase + kc,      (char*)&Al[0][0] + (tid + 256) * 16);
        gl_lds16(arow0 + cbase + 32 + kc, (char*)&Al[1][0] + tid * 16);
        gl_lds16(arow1 + cbase + 32 + kc, (char*)&Al[1][0] + (tid + 256) * 16);
        gl_lds16(Bt + (size_t)(n0 + rA0) * K_ + kk + kc,      (char*)&Bl[0][0] + tid * 16);
        gl_lds16(Bt + (size_t)(n0 + rA1) * K_ + kk + kc,      (char*)&Bl[0][0] + (tid + 256) * 16);
        gl_lds16(Bt + (size_t)(n0 + rA0) * K_ + kk + 32 + kc, (char*)&Bl[1][0] + tid * 16);
        gl_lds16(Bt + (size_t)(n0 + rA1) * K_ + kk + 32 + kc, (char*)&Bl[1][0] + (tid + 256) * 16);
        __syncthreads();

#pragma unroll
        for (int s = 0; s < 2; s++) {
            bf16x8 af[4], bfr[4];
#pragma unroll
            for (int i = 0; i < 4; i++)
                af[i] = *(const bf16x8*)(&Al[s][0] + (wm + i * 16 + lr) * 32 + kq * 8);
#pragma unroll
            for (int i = 0; i < 4; i++)
                bfr[i] = *(const bf16x8*)(&Bl[s][0] + (wn + i * 16 + lr) * 32 + kq * 8);
#pragma unroll
            for (int i = 0; i < 4; i++)
#pragma unroll
                for (int j = 0; j < 4; j++)
                    acc[i][j] = __builtin_amdgcn_mfma_f32_16x16x32_bf16(
                        af[i], bfr[j], acc[i][j], 0, 0, 0);
        }
    }

    const int nb  = n0 + wn;
    const int u3  = lane & 7;
    const int m0v = ((lane >> 3) & 1) * 4;
    const bool is_r = nb < NRS;

    float bj[4];
#pragma unroll
    for (int j = 0; j < 4; j++) bj[j] = biasP[nb + j * 16 + lr];

#pragma unroll
    for (int i = 0; i < 4; i++) {
        const int rowb = m0 + wm + i * 16 + kq * 4;
#pragma unroll
        for (int r = 0; r < 4; r++) {
            const int row = rowb + r;
            float z[4], mx = -1e30f;
#pragma unroll
            for (int j = 0; j < 4; j++) {
                float v = acc[i][j][r] + bj[j];
                float d = v - (float)(m0v + j) * LNT;
                z[j] = -d * d;
                mx = fmaxf(mx, z[j]);
            }
            mx = fmaxf(mx, __shfl_xor(mx, 8, 64));
            float e[4], sum = 0.f;
#pragma unroll
            for (int j = 0; j < 4; j++) { e[j] = __expf(z[j] - mx); sum += e[j]; }
            sum += __shfl_xor(sum, 8, 64);
            const float inv = 1.0f / sum;
            if (is_r) {
                bf16x4 h4 = *(const bf16x4*)(hhat + (size_t)row * NRS + nb + u3 * 8 + m0v);
                float rhv = 0.f;
#pragma unroll
                for (int j = 0; j < 4; j++) rhv += e[j] * inv * (float)h4[j];
                rhv += __shfl_xor(rhv, 8, 64);
                if ((lane & 8) == 0)
                    rh[(size_t)row * U_ + (nb >> 3) + u3] = (bf16_t)rhv;
            } else {
                bf16x4 pv;
#pragma unroll
                for (int j = 0; j < 4; j++) pv[j] = (bf16_t)(e[j] * inv);
                *(bf16x4*)(sbuf + (size_t)row * NRS + (nb - NRS) + u3 * 8 + m0v) = pv;
            }
        }
    }
}

// ---------------------------------------------------------------------------
// q GEMM (64x64 tiles, grid 64x8=512) + fused state update; BK=64 dual
// sub-tile staging like gemm_rs_ep.
// ---------------------------------------------------------------------------
__global__ __launch_bounds__(256) void gemm_q_up(
    const bf16_t* __restrict__ xt,     // [B_][F_]
    const bf16_t* __restrict__ rh,     // [B_][U_]
    const bf16_t* __restrict__ Bq,     // WqT [U_][K_]
    const float*  __restrict__ bq,
    const bf16_t* __restrict__ sbuf,
    bf16_t* __restrict__ hhat,
    bf16_t* __restrict__ hnext)        // [B_][U_]
{
    __shared__ bf16_t Al[2][64 * 32];
    __shared__ bf16_t Bl[2][64 * 32];

    const int tid  = threadIdx.x;
    const int lane = tid & 63;
    const int wave = tid >> 6;
    const int m0 = blockIdx.x * 64;
    const int n0 = blockIdx.y * 64;
    const int wm = (wave & 1) * 32;
    const int wn = (wave >> 1) * 32;
    const int lr = lane & 15;
    const int kq = lane >> 4;

    f32x4 acc[2][2] = {};

    const int rA = tid >> 2;
    const int kc = (tid & 3) * 8;

    for (int kk = 0; kk < K_; kk += 64) {
        const bf16_t* arow;
        int cbase;
        if (kk < F_) { arow = xt + (size_t)(m0 + rA) * F_; cbase = kk; }
        else         { arow = rh + (size_t)(m0 + rA) * U_; cbase = kk - F_; }

        __syncthreads();
        gl_lds16(arow + cbase + kc,      (char*)&Al[0][0] + tid * 16);
        gl_lds16(arow + cbase + 32 + kc, (char*)&Al[1][0] + tid * 16);
        gl_lds16(Bq + (size_t)(n0 + rA) * K_ + kk + kc,      (char*)&Bl[0][0] + tid * 16);
        gl_lds16(Bq + (size_t)(n0 + rA) * K_ + kk + 32 + kc, (char*)&Bl[1][0] + tid * 16);
        __syncthreads();

#pragma unroll
        for (int s = 0; s < 2; s++) {
            bf16x8 af[2], bfr[2];
#pragma unroll
            for (int i = 0; i < 2; i++)
                af[i] = *(const bf16x8*)(&Al[s][0] + (wm + i * 16 + lr) * 32 + kq * 8);
#pragma unroll
            for (int i = 0; i < 2; i++)
                bfr[i] = *(const bf16x8*)(&Bl[s][0] + (wn + i * 16 + lr) * 32 + kq * 8);
#pragma unroll
            for (int i = 0; i < 2; i++)
#pragma unroll
                for (int j = 0; j < 2; j++)
                    acc[i][j] = __builtin_amdgcn_mfma_f32_16x16x32_bf16(
                        af[i], bfr[j], acc[i][j], 0, 0, 0);
        }
    }

    const float DEC[8] = {0.0f, 0.9658531f, 0.9827783f, 0.9884856f,
                          0.9913518f, 0.9930754f, 0.9942261f, 0.9950489f};

#pragma unroll
    for (int i = 0; i < 2; i++) {
        const int rowb = m0 + wm + i * 16 + kq * 4;
#pragma unroll
        for (int j = 0; j < 2; j++) {
            const int u = n0 + wn + j * 16 + lr;
            const float bv = bq[u];
#pragma unroll
            for (int r = 0; r < 4; r++) {
                const int row = rowb + r;
                const float q = tanhf(acc[i][j][r] + bv);
                const size_t base = (size_t)row * NRS + u * 8;
                bf16x8 s8 = *(const bf16x8*)(sbuf + base);
                bf16x8 h8 = *(const bf16x8*)(hhat + base);
                bf16x8 ho;
                float hs = 0.f;
#pragma unroll
                for (int m = 0; m < 8; m++) {
                    float s = (float)s8[m];
                    float h = (float)h8[m];
                    float hn = ((1.f - s) * h + s * q) * DEC[m];
                    ho[m] = (bf16_t)hn;
                    hs += hn;
                }
                *(bf16x8*)(hhat + base) = ho;
                hnext[(size_t)row * U_ + u] = (bf16_t)hs;
            }
        }
    }
}

// dst[p][K_] = bf16(src[K_][NRS] col L), rows permuted within 64-groups.
__global__ void transpose_perm(const float* __restrict__ src, bf16_t* __restrict__ dst) {
    __shared__ float tl[32][33];
    int k0 = blockIdx.x * 32, n0 = blockIdx.y * 32;
    int tx = threadIdx.x & 31, ty = threadIdx.x >> 5;
#pragma unroll
    for (int i = 0; i < 32; i += 8)
        tl[ty + i][tx] = src[(size_t)(k0 + ty + i) * NRS + n0 + tx];
    __syncthreads();
#pragma unroll
    for (int i = 0; i < 32; i += 8) {
        int n = n0 + ty + i;
        int m = n & 7, u3v = (n >> 3) & 7;
        int p = (n & ~63) + (m & 3) * 16 + (m >> 2) * 8 + u3v;
        dst[(size_t)p * K_ + k0 + tx] = (bf16_t)tl[tx][ty + i];
    }
}

// plain transpose: dst[N][K_] = bf16(src[K_][N]^T)
__global__ void transpose_plain(const float* __restrict__ src, bf16_t* __restrict__ dst, int N) {
    __shared__ float tl[32][33];
    int k0 = blockIdx.x * 32, n0 = blockIdx.y * 32;
    int tx = threadIdx.x & 31, ty = threadIdx.x >> 5;
#pragma unroll
    for (int i = 0; i < 32; i += 8)
        tl[ty + i][tx] = src[(size_t)(k0 + ty + i) * N + n0 + tx];
    __syncthreads();
#pragma unroll
    for (int i = 0; i < 32; i += 8)
        dst[(size_t)(n0 + ty + i) * K_ + k0 + tx] = (bf16_t)tl[tx][ty + i];
}

__global__ void bias_perm(const float* __restrict__ b_r, const float* __restrict__ b_s,
                          float* __restrict__ biasP) {
    int p = blockIdx.x * 256 + threadIdx.x;  // NC
    int pr = p & 63, j = pr >> 4, lr = pr & 15;
    int L = (p & ~63) + (lr & 7) * 8 + ((lr >> 3) & 1) * 4 + j;
    biasP[p] = (L < NRS) ? b_r[L] : b_s[L - NRS];
}

// xall[t][b][f] = bf16(x[b][t][f])
__global__ void xall_build(const float* __restrict__ x, bf16_t* __restrict__ xall) {
    int idx = blockIdx.x * 256 + threadIdx.x;  // B_*T_*F_
    int b = idx >> 12;
    int rem = idx & 4095;
    int t = rem >> 8, f = rem & 255;
    xall[((size_t)t * B_ + b) * F_ + f] = (bf16_t)x[idx];
}

// out[b,t,:] = hnext[b,:] @ Wout + bout
__global__ void out_k(const bf16_t* __restrict__ hnext,
                      const float* __restrict__ Wout,
                      const float* __restrict__ bout,
                      float* __restrict__ out, int t) {
    int b = blockIdx.x;
    int lane = threadIdx.x;  // 64
    float p0 = 0, p1 = 0, p2 = 0;
    for (int u = lane; u < U_; u += 64) {
        float h = (float)hnext[(size_t)b * U_ + u];
        p0 += h * Wout[u * 3 + 0];
        p1 += h * Wout[u * 3 + 1];
        p2 += h * Wout[u * 3 + 2];
    }
    for (int off = 32; off; off >>= 1) {
        p0 += __shfl_down(p0, off, 64);
        p1 += __shfl_down(p1, off, 64);
        p2 += __shfl_down(p2, off, 64);
    }
    if (lane == 0) {
        size_t o = ((size_t)b * T_ + t) * 3;
        out[o + 0] = p0 + bout[0];
        out[o + 1] = p1 + bout[1];
        out[o + 2] = p2 + bout[2];
    }
}

extern "C" void kernel_launch(void* const* d_in, const int* in_sizes, int n_in,
                              void* d_out, int out_size, void* d_ws, size_t ws_size,
                              hipStream_t stream) {
    const float* x   = (const float*)d_in[0];
    const float* W_r = (const float*)d_in[1];
    const float* b_r = (const float*)d_in[2];
    const float* W_q = (const float*)d_in[3];
    const float* b_q = (const float*)d_in[4];
    const float* W_s = (const float*)d_in[5];
    const float* b_s = (const float*)d_in[6];
    const float* W_o = (const float*)d_in[7];
    const float* b_o = (const float*)d_in[8];
    float* out = (float*)d_out;

    char* ws = (char*)d_ws;
    bf16_t* hhat  = (bf16_t*)ws; ws += (size_t)B_ * NRS * 2;     // 32 MB
    bf16_t* sbuf  = (bf16_t*)ws; ws += (size_t)B_ * NRS * 2;     // 32 MB
    bf16_t* xall  = (bf16_t*)ws; ws += (size_t)B_ * T_ * F_ * 2; // 32 MB
    bf16_t* hA    = (bf16_t*)ws; ws += (size_t)B_ * U_ * 2;      // 4 MB
    bf16_t* hB    = (bf16_t*)ws; ws += (size_t)B_ * U_ * 2;      // 4 MB
    bf16_t* rh    = (bf16_t*)ws; ws += (size_t)B_ * U_ * 2;      // 4 MB
    bf16_t* WrsT  = (bf16_t*)ws; ws += (size_t)NC * K_ * 2;      // 12 MB
    bf16_t* WqT   = (bf16_t*)ws; ws += (size_t)U_ * K_ * 2;      // 0.75 MB
    float*  biasP = (float*)ws;  ws += (size_t)NC * 4;           // 32 KB

    hipMemsetAsync(hhat, 0, (size_t)B_ * NRS * 2, stream);
    hipMemsetAsync(hA, 0, (size_t)B_ * U_ * 2, stream);
    xall_build<<<B_ * T_ * F_ / 256, 256, 0, stream>>>(x, xall);
    transpose_perm<<<dim3(K_ / 32, NRS / 32), 256, 0, stream>>>(W_r, WrsT);
    transpose_perm<<<dim3(K_ / 32, NRS / 32), 256, 0, stream>>>(W_s, WrsT + (size_t)NRS * K_);
    transpose_plain<<<dim3(K_ / 32, U_ / 32), 256, 0, stream>>>(W_q, WqT, U_);
    bias_perm<<<NC / 256, 256, 0, stream>>>(b_r, b_s, biasP);

    for (int t = 0; t < T_; t++) {
        const bf16_t* xt = xall + (size_t)t * B_ * F_;
        const bf16_t* hp = (t & 1) ? hB : hA;
        bf16_t*       hn = (t & 1) ? hA : hB;
        gemm_rs_ep<<<dim3(32, 64), 256, 0, stream>>>(xt, hp, WrsT, biasP, hhat, rh, sbuf);
        gemm_q_up<<<dim3(64, 8), 256, 0, stream>>>(xt, rh, WqT, b_q, sbuf, hhat, hn);
        out_k<<<B_, 64, 0, stream>>>(hn, W_o, b_o, out, t);
    }
}

// Round 9
// 1605.212 us; speedup vs baseline: 12.5038x; 1.0855x over previous
//
#include <hip/hip_runtime.h>
#include <hip/hip_bf16.h>
#include <math.h>

#define B_   4096
#define T_   16
#define F_   256
#define U_   512
#define M_   8
#define K_   768    // F+U
#define NRS  4096   // U*M
#define NC   8192   // combined R|S output cols
#define LNT  1.1512925f  // 0.5*ln(10)

typedef __bf16 bf16_t;
typedef bf16_t bf16x8 __attribute__((ext_vector_type(8)));
typedef bf16_t bf16x4 __attribute__((ext_vector_type(4)));
typedef float  f32x4  __attribute__((ext_vector_type(4)));

__device__ inline void gl_lds16(const void* g, void* lds) {
    __builtin_amdgcn_global_load_lds(
        (const __attribute__((address_space(1))) unsigned int*)g,
        (__attribute__((address_space(3))) unsigned int*)lds, 16, 0, 0);
}

// ---------------------------------------------------------------------------
// Combined R|S GEMM with fused softmax epilogue. BK=64 as two 32-col
// sub-tiles (conflict-free stride-64B LDS rows). launch_bounds(256,4):
// target <=128 unified regs -> 4 blocks/CU (was 144 regs -> 3).
// Softmax WITHOUT max-subtraction: z=-d^2<=0, exp in (0,1]; den==0 needs a
// ~9.4-sigma GEMM output -> impossible at our scales.
// ---------------------------------------------------------------------------
__global__ __launch_bounds__(256, 4) void gemm_rs_ep(
    const bf16_t* __restrict__ xt,     // [B_][F_]
    const bf16_t* __restrict__ hprev,  // [B_][U_]
    const bf16_t* __restrict__ Bt,     // WrsT [NC][K_] (perm)
    const float*  __restrict__ biasP,  // [NC] (perm)
    const bf16_t* __restrict__ hhat,   // [B_][NRS]
    bf16_t* __restrict__ rh,           // [B_][U_]
    bf16_t* __restrict__ sbuf)         // [B_][NRS]
{
    __shared__ bf16_t Al[2][128 * 32];
    __shared__ bf16_t Bl[2][128 * 32];

    const int tid  = threadIdx.x;
    const int lane = tid & 63;
    const int wave = tid >> 6;
    const int m0 = blockIdx.x * 128;
    const int n0 = blockIdx.y * 128;
    const int wm = (wave & 1) * 64;
    const int wn = (wave >> 1) * 64;
    const int lr = lane & 15;
    const int kq = lane >> 4;

    f32x4 acc[4][4] = {};

    const int rA0 = tid >> 2, rA1 = 64 + (tid >> 2);
    const int kc  = (tid & 3) * 8;

    for (int kk = 0; kk < K_; kk += 64) {
        const bf16_t* arow0;
        const bf16_t* arow1;
        int cbase;
        if (kk < F_) { arow0 = xt + (size_t)(m0 + rA0) * F_;
                       arow1 = xt + (size_t)(m0 + rA1) * F_; cbase = kk; }
        else         { arow0 = hprev + (size_t)(m0 + rA0) * U_;
                       arow1 = hprev + (size_t)(m0 + rA1) * U_; cbase = kk - F_; }

        __syncthreads();
        gl_lds16(arow0 + cbase + kc,      (char*)&Al[0][0] + tid * 16);
        gl_lds16(arow1 + cbase + kc,      (char*)&Al[0][0] + (tid + 256) * 16);
        gl_lds16(arow0 + cbase + 32 + kc, (char*)&Al[1][0] + tid * 16);
        gl_lds16(arow1 + cbase + 32 + kc, (char*)&Al[1][0] + (tid + 256) * 16);
        gl_lds16(Bt + (size_t)(n0 + rA0) * K_ + kk + kc,      (char*)&Bl[0][0] + tid * 16);
        gl_lds16(Bt + (size_t)(n0 + rA1) * K_ + kk + kc,      (char*)&Bl[0][0] + (tid + 256) * 16);
        gl_lds16(Bt + (size_t)(n0 + rA0) * K_ + kk + 32 + kc, (char*)&Bl[1][0] + tid * 16);
        gl_lds16(Bt + (size_t)(n0 + rA1) * K_ + kk + 32 + kc, (char*)&Bl[1][0] + (tid + 256) * 16);
        __syncthreads();

#pragma unroll
        for (int s = 0; s < 2; s++) {
            bf16x8 af[4], bfr[4];
#pragma unroll
            for (int i = 0; i < 4; i++)
                af[i] = *(const bf16x8*)(&Al[s][0] + (wm + i * 16 + lr) * 32 + kq * 8);
#pragma unroll
            for (int i = 0; i < 4; i++)
                bfr[i] = *(const bf16x8*)(&Bl[s][0] + (wn + i * 16 + lr) * 32 + kq * 8);
#pragma unroll
            for (int i = 0; i < 4; i++)
#pragma unroll
                for (int j = 0; j < 4; j++)
                    acc[i][j] = __builtin_amdgcn_mfma_f32_16x16x32_bf16(
                        af[i], bfr[j], acc[i][j], 0, 0, 0);
        }
    }

    const int nb  = n0 + wn;
    const int u3  = lane & 7;
    const int m0v = ((lane >> 3) & 1) * 4;
    const bool is_r = nb < NRS;

    float bj[4];
#pragma unroll
    for (int j = 0; j < 4; j++) bj[j] = biasP[nb + j * 16 + lr];

#pragma unroll
    for (int i = 0; i < 4; i++) {
        const int rowb = m0 + wm + i * 16 + kq * 4;
#pragma unroll
        for (int r = 0; r < 4; r++) {
            const int row = rowb + r;
            float e[4], sum = 0.f;
#pragma unroll
            for (int j = 0; j < 4; j++) {
                float v = acc[i][j][r] + bj[j];
                float d = v - (float)(m0v + j) * LNT;
                e[j] = __expf(-d * d);
                sum += e[j];
            }
            sum += __shfl_xor(sum, 8, 64);
            const float inv = 1.0f / sum;
            if (is_r) {
                bf16x4 h4 = *(const bf16x4*)(hhat + (size_t)row * NRS + nb + u3 * 8 + m0v);
                float rhv = 0.f;
#pragma unroll
                for (int j = 0; j < 4; j++) rhv += e[j] * inv * (float)h4[j];
                rhv += __shfl_xor(rhv, 8, 64);
                if ((lane & 8) == 0)
                    rh[(size_t)row * U_ + (nb >> 3) + u3] = (bf16_t)rhv;
            } else {
                bf16x4 pv;
#pragma unroll
                for (int j = 0; j < 4; j++) pv[j] = (bf16_t)(e[j] * inv);
                *(bf16x4*)(sbuf + (size_t)row * NRS + (nb - NRS) + u3 * 8 + m0v) = pv;
            }
        }
    }
}

// ---------------------------------------------------------------------------
// q GEMM (64x64 tiles, grid 64x8=512) + fused state update; writes this
// step's hidden into hall slice t (persistent; next rs reads it as hprev).
// ---------------------------------------------------------------------------
__global__ __launch_bounds__(256) void gemm_q_up(
    const bf16_t* __restrict__ xt,     // [B_][F_]
    const bf16_t* __restrict__ rh,     // [B_][U_]
    const bf16_t* __restrict__ Bq,     // WqT [U_][K_]
    const float*  __restrict__ bq,
    const bf16_t* __restrict__ sbuf,
    bf16_t* __restrict__ hhat,
    bf16_t* __restrict__ hnext)        // hall slice t: [B_][U_]
{
    __shared__ bf16_t Al[2][64 * 32];
    __shared__ bf16_t Bl[2][64 * 32];

    const int tid  = threadIdx.x;
    const int lane = tid & 63;
    const int wave = tid >> 6;
    const int m0 = blockIdx.x * 64;
    const int n0 = blockIdx.y * 64;
    const int wm = (wave & 1) * 32;
    const int wn = (wave >> 1) * 32;
    const int lr = lane & 15;
    const int kq = lane >> 4;

    f32x4 acc[2][2] = {};

    const int rA = tid >> 2;
    const int kc = (tid & 3) * 8;

    for (int kk = 0; kk < K_; kk += 64) {
        const bf16_t* arow;
        int cbase;
        if (kk < F_) { arow = xt + (size_t)(m0 + rA) * F_; cbase = kk; }
        else         { arow = rh + (size_t)(m0 + rA) * U_; cbase = kk - F_; }

        __syncthreads();
        gl_lds16(arow + cbase + kc,      (char*)&Al[0][0] + tid * 16);
        gl_lds16(arow + cbase + 32 + kc, (char*)&Al[1][0] + tid * 16);
        gl_lds16(Bq + (size_t)(n0 + rA) * K_ + kk + kc,      (char*)&Bl[0][0] + tid * 16);
        gl_lds16(Bq + (size_t)(n0 + rA) * K_ + kk + 32 + kc, (char*)&Bl[1][0] + tid * 16);
        __syncthreads();

#pragma unroll
        for (int s = 0; s < 2; s++) {
            bf16x8 af[2], bfr[2];
#pragma unroll
            for (int i = 0; i < 2; i++)
                af[i] = *(const bf16x8*)(&Al[s][0] + (wm + i * 16 + lr) * 32 + kq * 8);
#pragma unroll
            for (int i = 0; i < 2; i++)
                bfr[i] = *(const bf16x8*)(&Bl[s][0] + (wn + i * 16 + lr) * 32 + kq * 8);
#pragma unroll
            for (int i = 0; i < 2; i++)
#pragma unroll
                for (int j = 0; j < 2; j++)
                    acc[i][j] = __builtin_amdgcn_mfma_f32_16x16x32_bf16(
                        af[i], bfr[j], acc[i][j], 0, 0, 0);
        }
    }

    const float DEC[8] = {0.0f, 0.9658531f, 0.9827783f, 0.9884856f,
                          0.9913518f, 0.9930754f, 0.9942261f, 0.9950489f};

#pragma unroll
    for (int i = 0; i < 2; i++) {
        const int rowb = m0 + wm + i * 16 + kq * 4;
#pragma unroll
        for (int j = 0; j < 2; j++) {
            const int u = n0 + wn + j * 16 + lr;
            const float bv = bq[u];
#pragma unroll
            for (int r = 0; r < 4; r++) {
                const int row = rowb + r;
                const float q = tanhf(acc[i][j][r] + bv);
                const size_t base = (size_t)row * NRS + u * 8;
                bf16x8 s8 = *(const bf16x8*)(sbuf + base);
                bf16x8 h8 = *(const bf16x8*)(hhat + base);
                bf16x8 ho;
                float hs = 0.f;
#pragma unroll
                for (int m = 0; m < 8; m++) {
                    float s = (float)s8[m];
                    float h = (float)h8[m];
                    float hn = ((1.f - s) * h + s * q) * DEC[m];
                    ho[m] = (bf16_t)hn;
                    hs += hn;
                }
                *(bf16x8*)(hhat + base) = ho;
                hnext[(size_t)row * U_ + u] = (bf16_t)hs;
            }
        }
    }
}

// dst[p][K_] = bf16(src[K_][NRS] col L), rows permuted within 64-groups.
__global__ void transpose_perm(const float* __restrict__ src, bf16_t* __restrict__ dst) {
    __shared__ float tl[32][33];
    int k0 = blockIdx.x * 32, n0 = blockIdx.y * 32;
    int tx = threadIdx.x & 31, ty = threadIdx.x >> 5;
#pragma unroll
    for (int i = 0; i < 32; i += 8)
        tl[ty + i][tx] = src[(size_t)(k0 + ty + i) * NRS + n0 + tx];
    __syncthreads();
#pragma unroll
    for (int i = 0; i < 32; i += 8) {
        int n = n0 + ty + i;
        int m = n & 7, u3v = (n >> 3) & 7;
        int p = (n & ~63) + (m & 3) * 16 + (m >> 2) * 8 + u3v;
        dst[(size_t)p * K_ + k0 + tx] = (bf16_t)tl[tx][ty + i];
    }
}

// plain transpose: dst[N][K_] = bf16(src[K_][N]^T)
__global__ void transpose_plain(const float* __restrict__ src, bf16_t* __restrict__ dst, int N) {
    __shared__ float tl[32][33];
    int k0 = blockIdx.x * 32, n0 = blockIdx.y * 32;
    int tx = threadIdx.x & 31, ty = threadIdx.x >> 5;
#pragma unroll
    for (int i = 0; i < 32; i += 8)
        tl[ty + i][tx] = src[(size_t)(k0 + ty + i) * N + n0 + tx];
    __syncthreads();
#pragma unroll
    for (int i = 0; i < 32; i += 8)
        dst[(size_t)(n0 + ty + i) * K_ + k0 + tx] = (bf16_t)tl[tx][ty + i];
}

__global__ void bias_perm(const float* __restrict__ b_r, const float* __restrict__ b_s,
                          float* __restrict__ biasP) {
    int p = blockIdx.x * 256 + threadIdx.x;  // NC
    int pr = p & 63, j = pr >> 4, lr = pr & 15;
    int L = (p & ~63) + (lr & 7) * 8 + ((lr >> 3) & 1) * 4 + j;
    biasP[p] = (L < NRS) ? b_r[L] : b_s[L - NRS];
}

// xall[t][b][f] = bf16(x[b][t][f])
__global__ void xall_build(const float* __restrict__ x, bf16_t* __restrict__ xall) {
    int idx = blockIdx.x * 256 + threadIdx.x;  // B_*T_*F_
    int b = idx >> 12;
    int rem = idx & 4095;
    int t = rem >> 8, f = rem & 255;
    xall[((size_t)t * B_ + b) * F_ + f] = (bf16_t)x[idx];
}

// One launch for all T steps: out[b,t,:] = hall[t][b][:] @ Wout + bout.
// One wave per (t,b) row; bf16x8 coalesced h read.
__global__ __launch_bounds__(256) void out_all(
    const bf16_t* __restrict__ hall,   // [T_][B_][U_] (slices 1..16 of alloc)
    const float* __restrict__ Wout,
    const float* __restrict__ bout,
    float* __restrict__ out)
{
    int row = blockIdx.x * 4 + (threadIdx.x >> 6);  // t*B_ + b
    int lane = threadIdx.x & 63;
    bf16x8 h8 = *(const bf16x8*)(hall + (size_t)row * U_ + lane * 8);
    float p0 = 0, p1 = 0, p2 = 0;
#pragma unroll
    for (int k = 0; k < 8; k++) {
        float h = (float)h8[k];
        int u = lane * 8 + k;
        p0 += h * Wout[u * 3 + 0];
        p1 += h * Wout[u * 3 + 1];
        p2 += h * Wout[u * 3 + 2];
    }
    for (int off = 32; off; off >>= 1) {
        p0 += __shfl_down(p0, off, 64);
        p1 += __shfl_down(p1, off, 64);
        p2 += __shfl_down(p2, off, 64);
    }
    if (lane == 0) {
        int t = row >> 12, b = row & (B_ - 1);
        size_t o = ((size_t)b * T_ + t) * 3;
        out[o + 0] = p0 + bout[0];
        out[o + 1] = p1 + bout[1];
        out[o + 2] = p2 + bout[2];
    }
}

extern "C" void kernel_launch(void* const* d_in, const int* in_sizes, int n_in,
                              void* d_out, int out_size, void* d_ws, size_t ws_size,
                              hipStream_t stream) {
    const float* x   = (const float*)d_in[0];
    const float* W_r = (const float*)d_in[1];
    const float* b_r = (const float*)d_in[2];
    const float* W_q = (const float*)d_in[3];
    const float* b_q = (const float*)d_in[4];
    const float* W_s = (const float*)d_in[5];
    const float* b_s = (const float*)d_in[6];
    const float* W_o = (const float*)d_in[7];
    const float* b_o = (const float*)d_in[8];
    float* out = (float*)d_out;

    char* ws = (char*)d_ws;
    bf16_t* hhat  = (bf16_t*)ws; ws += (size_t)B_ * NRS * 2;         // 32 MB
    bf16_t* sbuf  = (bf16_t*)ws; ws += (size_t)B_ * NRS * 2;         // 32 MB
    bf16_t* xall  = (bf16_t*)ws; ws += (size_t)B_ * T_ * F_ * 2;     // 32 MB
    bf16_t* hall  = (bf16_t*)ws; ws += (size_t)(T_ + 1) * B_ * U_ * 2; // 68 MB
    bf16_t* rh    = (bf16_t*)ws; ws += (size_t)B_ * U_ * 2;          // 4 MB
    bf16_t* WrsT  = (bf16_t*)ws; ws += (size_t)NC * K_ * 2;          // 12 MB
    bf16_t* WqT   = (bf16_t*)ws; ws += (size_t)U_ * K_ * 2;          // 0.75 MB
    float*  biasP = (float*)ws;  ws += (size_t)NC * 4;               // 32 KB

    hipMemsetAsync(hhat, 0, (size_t)B_ * NRS * 2, stream);
    hipMemsetAsync(hall, 0, (size_t)B_ * U_ * 2, stream);  // slice 0 = h(-1)=0
    xall_build<<<B_ * T_ * F_ / 256, 256, 0, stream>>>(x, xall);
    transpose_perm<<<dim3(K_ / 32, NRS / 32), 256, 0, stream>>>(W_r, WrsT);
    transpose_perm<<<dim3(K_ / 32, NRS / 32), 256, 0, stream>>>(W_s, WrsT + (size_t)NRS * K_);
    transpose_plain<<<dim3(K_ / 32, U_ / 32), 256, 0, stream>>>(W_q, WqT, U_);
    bias_perm<<<NC / 256, 256, 0, stream>>>(b_r, b_s, biasP);

    for (int t = 0; t < T_; t++) {
        const bf16_t* xt = xall + (size_t)t * B_ * F_;
        const bf16_t* hp = hall + (size_t)t * B_ * U_;        // h(t-1)
        bf16_t*       hn = hall + (size_t)(t + 1) * B_ * U_;  // h(t)
        gemm_rs_ep<<<dim3(32, 64), 256, 0, stream>>>(xt, hp, WrsT, biasP, hhat, rh, sbuf);
        gemm_q_up<<<dim3(64, 8), 256, 0, stream>>>(xt, rh, WqT, b_q, sbuf, hhat, hn);
    }
    out_all<<<B_ * T_ / 4, 256, 0, stream>>>(hall + (size_t)B_ * U_, W_o, b_o, out);
}